// Round 2
// baseline (697.047 us; speedup 1.0000x reference)
//
#include <hip/hip_runtime.h>

#define N_ITEMS 500000
#define EMBED 64
#define BATCH 1024
#define TILE 128
#define NCHUNK ((N_ITEMS + TILE - 1) / TILE)   // 3907

typedef __attribute__((ext_vector_type(8))) __bf16 bf16x8;
typedef __attribute__((ext_vector_type(4))) float f32x4;

// fp32 -> (hi bf16, lo bf16) split using HW RNE cvt; residual error ~2^-18|x|
__device__ __forceinline__ void cvt8v(const f32x4 a, const f32x4 b,
                                      bf16x8& H, bf16x8& L) {
#pragma unroll
  for (int k = 0; k < 4; ++k) {
    __bf16 hb = (__bf16)a[k];
    H[k] = hb;
    L[k] = (__bf16)(a[k] - (float)hb);
  }
#pragma unroll
  for (int k = 0; k < 4; ++k) {
    __bf16 hb = (__bf16)b[k];
    H[4 + k] = hb;
    L[4 + k] = (__bf16)(b[k] - (float)hb);
  }
}

// LDS layout: row stride 64 elems (128 B), granule (8 elems = 16 B) XOR-swizzled
// by (row & 7) -> uniform bank use for both the staging writes and frag reads.
__global__ __launch_bounds__(256, 2)
void sim_kernel(const float* __restrict__ emb, const int* __restrict__ idx,
                unsigned long long* __restrict__ best, int nbj) {
  __shared__ unsigned short Ah[TILE * 64];
  __shared__ unsigned short Al[TILE * 64];
  __shared__ unsigned short Bh[TILE * 64];
  __shared__ unsigned short Bl[TILE * 64];
  __shared__ int sidx[TILE];

  const int tid  = threadIdx.x;
  const int lane = tid & 63;
  const int wv   = tid >> 6;
  const int wm   = wv >> 1;      // 2x2 wave grid, 64x64 tile per wave
  const int wn   = wv & 1;
  const int l15  = lane & 15;
  const int kq   = lane >> 4;    // 0..3
  const int sw   = lane & 7;     // read-side swizzle (== row&7 for frag rows)
  const int mt   = blockIdx.x & 7;
  const int jg   = blockIdx.x >> 3;
  const int m0   = mt * TILE;

  const int lrow = tid >> 1;     // row this thread stages
  const int half = tid & 1;
  const int c0   = half * 32;
  const int swr  = lrow & 7;     // write-side swizzle

  // ---- stage A (gathered query rows) ----
  {
    int q = m0 + lrow;
    int row = idx[q] - 1;
    if (row < 0) row += N_ITEMS;           // numpy negative-index wrap
    if (half == 0) sidx[lrow] = row;
    const float* src = emb + (size_t)row * EMBED + c0;
#pragma unroll
    for (int i = 0; i < 4; ++i) {
      f32x4 a = *(const f32x4*)(src + i * 8);
      f32x4 b = *(const f32x4*)(src + i * 8 + 4);
      bf16x8 H, L;
      cvt8v(a, b, H, L);
      const int g = ((half * 4 + i) ^ swr) * 8;
      *(bf16x8*)(Ah + lrow * 64 + g) = H;
      *(bf16x8*)(Al + lrow * 64 + g) = L;
    }
  }

  // ---- prefetch first B chunk into registers ----
  f32x4 raw[8];
  {
    int jr = jg * TILE + lrow;
    if (jr >= N_ITEMS) jr = N_ITEMS - 1;   // clamp; masked later via jok
    const float* src = emb + (size_t)jr * EMBED + c0;
#pragma unroll
    for (int i = 0; i < 8; ++i) raw[i] = *(const f32x4*)(src + i * 4);
  }

  __syncthreads();   // A staged

  // ---- hoist A-hi fragments for the whole kernel (invariant over chunks) ----
  bf16x8 ah[2][4];
#pragma unroll
  for (int ks = 0; ks < 2; ++ks)
#pragma unroll
    for (int am = 0; am < 4; ++am) {
      const int row = wm * 64 + am * 16 + l15;
      ah[ks][am] = *(const bf16x8*)(Ah + row * 64 + (((ks * 4 + kq) ^ sw) << 3));
    }

  int self_[16];
  float bs[16];
  unsigned bj[16];
#pragma unroll
  for (int am = 0; am < 4; ++am)
#pragma unroll
    for (int r = 0; r < 4; ++r) {
      const int sl = am * 4 + r;
      self_[sl] = sidx[wm * 64 + am * 16 + kq * 4 + r];
      bs[sl] = -3.4e38f;
      bj[sl] = 0xFFFFFFFFu;
    }

  f32x4 acc[4][4];

  for (int ch = jg; ch < NCHUNK; ch += nbj) {
    const int j0 = ch * TILE;

    // convert the prefetched chunk (overlaps nothing critical; HW cvt is cheap)
    bf16x8 Hc[4], Lc[4];
#pragma unroll
    for (int i = 0; i < 4; ++i) cvt8v(raw[2 * i], raw[2 * i + 1], Hc[i], Lc[i]);

    __syncthreads();   // previous iteration's B readers done
#pragma unroll
    for (int i = 0; i < 4; ++i) {
      const int g = ((half * 4 + i) ^ swr) * 8;
      *(bf16x8*)(Bh + lrow * 64 + g) = Hc[i];
      *(bf16x8*)(Bl + lrow * 64 + g) = Lc[i];
    }
    __syncthreads();   // B ready

    // issue next chunk's global loads; latency hidden under MFMA below
    {
      const int nch = ch + nbj;
      if (nch < NCHUNK) {
        int jr = nch * TILE + lrow;
        if (jr >= N_ITEMS) jr = N_ITEMS - 1;
        const float* src = emb + (size_t)jr * EMBED + c0;
#pragma unroll
        for (int i = 0; i < 8; ++i) raw[i] = *(const f32x4*)(src + i * 4);
      }
    }

    const f32x4 zero = {0.f, 0.f, 0.f, 0.f};
#pragma unroll
    for (int am = 0; am < 4; ++am)
#pragma unroll
      for (int bn = 0; bn < 4; ++bn)
        acc[am][bn] = zero;

#pragma unroll
    for (int ks = 0; ks < 2; ++ks) {
      const int kgo = (((ks * 4 + kq) ^ sw)) << 3;
      bf16x8 bh[4], bl[4], alf[4];
#pragma unroll
      for (int bn = 0; bn < 4; ++bn) {
        const int off = (wn * 64 + bn * 16 + l15) * 64 + kgo;
        bh[bn] = *(const bf16x8*)(Bh + off);
        bl[bn] = *(const bf16x8*)(Bl + off);
      }
#pragma unroll
      for (int am = 0; am < 4; ++am)
        alf[am] = *(const bf16x8*)(Al + (wm * 64 + am * 16 + l15) * 64 + kgo);

      // 3-term split product: hi*hi + lo*hi + hi*lo (frags shared across terms)
#pragma unroll
      for (int am = 0; am < 4; ++am)
#pragma unroll
        for (int bn = 0; bn < 4; ++bn)
          acc[am][bn] = __builtin_amdgcn_mfma_f32_16x16x32_bf16(
              ah[ks][am], bh[bn], acc[am][bn], 0, 0, 0);
#pragma unroll
      for (int am = 0; am < 4; ++am)
#pragma unroll
        for (int bn = 0; bn < 4; ++bn)
          acc[am][bn] = __builtin_amdgcn_mfma_f32_16x16x32_bf16(
              alf[am], bh[bn], acc[am][bn], 0, 0, 0);
#pragma unroll
      for (int am = 0; am < 4; ++am)
#pragma unroll
        for (int bn = 0; bn < 4; ++bn)
          acc[am][bn] = __builtin_amdgcn_mfma_f32_16x16x32_bf16(
              ah[ks][am], bl[bn], acc[am][bn], 0, 0, 0);
    }

    // running max/argmax (C layout: col=lane&15, row=(lane>>4)*4+reg)
#pragma unroll
    for (int bn = 0; bn < 4; ++bn) {
      const int jc = j0 + wn * 64 + bn * 16 + l15;
      const bool jok = jc < N_ITEMS;
#pragma unroll
      for (int am = 0; am < 4; ++am)
#pragma unroll
        for (int r = 0; r < 4; ++r) {
          const int sl = am * 4 + r;
          float v = acc[am][bn][r];
          v = (jok && jc != self_[sl]) ? v : -3.4e38f;
          if (v > bs[sl]) { bs[sl] = v; bj[sl] = (unsigned)jc; }
        }
    }
  }

  // ---- epilogue: per-row reduce over 32 column-groups, then atomic ----
  __syncthreads();
  float* Ss    = (float*)Bh;     // 128*32*4 = 16 KB (exact fit)
  unsigned* Sj = (unsigned*)Ah;  // 16 KB
  const int cg = wn * 16 + l15;
#pragma unroll
  for (int am = 0; am < 4; ++am)
#pragma unroll
    for (int r = 0; r < 4; ++r) {
      const int sl = am * 4 + r;
      const int rl = wm * 64 + am * 16 + kq * 4 + r;
      Ss[rl * 32 + cg] = bs[sl];
      Sj[rl * 32 + cg] = bj[sl];
    }
  __syncthreads();
  if (tid < TILE) {
    float b = -3.4e38f;
    unsigned j = 0xFFFFFFFFu;
    for (int c = 0; c < 32; ++c) {
      float s = Ss[tid * 32 + c];
      unsigned jj = Sj[tid * 32 + c];
      if (s > b || (s == b && jj < j)) { b = s; j = jj; }
    }
    union { float f; int i; unsigned u; } cv; cv.f = b;
    unsigned mu = (cv.i < 0) ? ~cv.u : (cv.u | 0x80000000u);
    unsigned long long key =
        ((unsigned long long)mu << 32) | (unsigned long long)(0xFFFFFFFFu - j);
    atomicMax(best + m0 + tid, key);
  }
}

__global__ void extract_kernel(const unsigned long long* __restrict__ best,
                               const float* __restrict__ mn,
                               const float* __restrict__ mx,
                               float* __restrict__ out) {
  int t = blockIdx.x * blockDim.x + threadIdx.x;
  if (t >= BATCH) return;
  unsigned long long k = best[t];
  unsigned mu = (unsigned)(k >> 32);
  unsigned j  = 0xFFFFFFFFu - (unsigned)(k & 0xFFFFFFFFull);
  union { unsigned u; float f; } cv;
  cv.u = (mu & 0x80000000u) ? (mu & 0x7FFFFFFFu) : ~mu;
  float s = cv.f;
  float lo = mn[0], hi = mx[0];
  out[t] = (float)(j + 1);
  out[BATCH + t] = (s - lo) / (hi - lo);
}

extern "C" void kernel_launch(void* const* d_in, const int* in_sizes, int n_in,
                              void* d_out, int out_size, void* d_ws, size_t ws_size,
                              hipStream_t stream) {
  const float* emb = (const float*)d_in[0];
  const int* idx   = (const int*)d_in[1];
  const float* mn  = (const float*)d_in[2];
  const float* mx  = (const float*)d_in[3];
  unsigned long long* best = (unsigned long long*)d_ws;

  hipMemsetAsync(d_ws, 0, BATCH * sizeof(unsigned long long), stream);

  const int nbj = 512;                 // 8 M-tiles x 512 chunk-groups = 4096 blocks
  sim_kernel<<<dim3(8 * nbj), dim3(256), 0, stream>>>(emb, idx, best, nbj);
  extract_kernel<<<dim3((BATCH + 255) / 256), dim3(256), 0, stream>>>(
      best, mn, mx, (float*)d_out);
}

// Round 3
// 470.516 us; speedup vs baseline: 1.4815x; 1.4815x over previous
//
#include <hip/hip_runtime.h>

#define N_ITEMS 500000
#define EMBED 64
#define BATCH 1024
#define JG 128                        // chunk-groups (grid = 4 M-blocks x JG)
#define NCH64 ((N_ITEMS + 63) / 64)   // 7813 chunks of 64 items

typedef __attribute__((ext_vector_type(8))) __bf16 bf16x8;
typedef __attribute__((ext_vector_type(4))) float f32x4;

// 8 fp32 -> hi bf16x8 + lo bf16x8 (HW RNE cvt; residual ~2^-18|x|)
__device__ __forceinline__ void cvt8v(const f32x4 a, const f32x4 b,
                                      bf16x8& H, bf16x8& L) {
#pragma unroll
  for (int k = 0; k < 4; ++k) {
    __bf16 hb = (__bf16)a[k];
    H[k] = hb;
    L[k] = (__bf16)(a[k] - (float)hb);
  }
#pragma unroll
  for (int k = 0; k < 4; ++k) {
    __bf16 hb = (__bf16)b[k];
    H[4 + k] = hb;
    L[4 + k] = (__bf16)(b[k] - (float)hb);
  }
}

// No LDS in the main loop: B fragments are loaded straight from global in
// MFMA layout (lane l: item row j0+bn*16+(l&15), k = (l>>4)*8..+8 per ks),
// A fragments hoisted in registers for the whole kernel.
__global__ __launch_bounds__(256, 2)
void sim_kernel(const float* __restrict__ emb, const int* __restrict__ idx,
                unsigned long long* __restrict__ best) {
  const int tid  = threadIdx.x;
  const int lane = tid & 63;
  const int wv   = tid >> 6;
  const int l15  = lane & 15;
  const int kq   = lane >> 4;           // 0..3
  const int mb   = blockIdx.x & 3;      // 4 M-blocks x 256 rows
  const int jg   = blockIdx.x >> 2;     // chunk-group
  const int m0   = mb * 256 + wv * 64;  // this wave's 64 query rows
  const int colbase = kq * 8;

  // ---- A fragments (gathered query rows), hi+lo, in registers ----
  bf16x8 ah[4][2], al[4][2];            // [am][ks]
#pragma unroll
  for (int am = 0; am < 4; ++am) {
    int row = idx[m0 + am * 16 + l15] - 1;
    if (row < 0) row += N_ITEMS;        // numpy negative-index wrap
    const float* src = emb + (size_t)row * EMBED + colbase;
    f32x4 r0 = *(const f32x4*)(src);
    f32x4 r1 = *(const f32x4*)(src + 4);
    f32x4 r2 = *(const f32x4*)(src + 32);
    f32x4 r3 = *(const f32x4*)(src + 36);
    cvt8v(r0, r1, ah[am][0], al[am][0]);
    cvt8v(r2, r3, ah[am][1], al[am][1]);
  }

  // per-slot (am, r) running best; slot covers row m0 + am*16 + kq*4 + r
  int self_[16];
  float bs[16];
  unsigned bj[16];
#pragma unroll
  for (int am = 0; am < 4; ++am)
#pragma unroll
    for (int r = 0; r < 4; ++r) {
      int row = idx[m0 + am * 16 + kq * 4 + r] - 1;
      if (row < 0) row += N_ITEMS;
      self_[am * 4 + r] = row;
      bs[am * 4 + r] = -3.4e38f;
      bj[am * 4 + r] = 0xFFFFFFFFu;
    }

  // ---- main loop: 64-item chunks, bn (16 items) at a time, 1-bn prefetch ----
  f32x4 raw[2][4];
  {
    int jr = jg * 64 + l15;
    if (jr >= N_ITEMS) jr = N_ITEMS - 1;
    const float* src = emb + (size_t)jr * EMBED + colbase;
    raw[0][0] = *(const f32x4*)(src);
    raw[0][1] = *(const f32x4*)(src + 4);
    raw[0][2] = *(const f32x4*)(src + 32);
    raw[0][3] = *(const f32x4*)(src + 36);
  }

  for (int c = jg; c < NCH64; c += JG) {
#pragma unroll
    for (int bn = 0; bn < 4; ++bn) {
      const int cur = bn & 1, nxt = cur ^ 1;
      {  // prefetch next bn (or next chunk's bn0); uniform condition
        const int nc  = (bn == 3) ? (c + JG) : c;
        const int nbn = (bn + 1) & 3;
        if (nc < NCH64) {
          int jr = nc * 64 + nbn * 16 + l15;
          if (jr >= N_ITEMS) jr = N_ITEMS - 1;
          const float* src = emb + (size_t)jr * EMBED + colbase;
          raw[nxt][0] = *(const f32x4*)(src);
          raw[nxt][1] = *(const f32x4*)(src + 4);
          raw[nxt][2] = *(const f32x4*)(src + 32);
          raw[nxt][3] = *(const f32x4*)(src + 36);
        }
      }
      bf16x8 bh0, bl0, bh1, bl1;
      cvt8v(raw[cur][0], raw[cur][1], bh0, bl0);
      cvt8v(raw[cur][2], raw[cur][3], bh1, bl1);

      const f32x4 zero = {0.f, 0.f, 0.f, 0.f};
      f32x4 acc[4];
#pragma unroll
      for (int am = 0; am < 4; ++am) acc[am] = zero;
      // 3-term split: hi*hi + lo*hi + hi*lo, both k-halves
#pragma unroll
      for (int am = 0; am < 4; ++am)
        acc[am] = __builtin_amdgcn_mfma_f32_16x16x32_bf16(ah[am][0], bh0, acc[am], 0, 0, 0);
#pragma unroll
      for (int am = 0; am < 4; ++am)
        acc[am] = __builtin_amdgcn_mfma_f32_16x16x32_bf16(al[am][0], bh0, acc[am], 0, 0, 0);
#pragma unroll
      for (int am = 0; am < 4; ++am)
        acc[am] = __builtin_amdgcn_mfma_f32_16x16x32_bf16(ah[am][0], bl0, acc[am], 0, 0, 0);
#pragma unroll
      for (int am = 0; am < 4; ++am)
        acc[am] = __builtin_amdgcn_mfma_f32_16x16x32_bf16(ah[am][1], bh1, acc[am], 0, 0, 0);
#pragma unroll
      for (int am = 0; am < 4; ++am)
        acc[am] = __builtin_amdgcn_mfma_f32_16x16x32_bf16(al[am][1], bh1, acc[am], 0, 0, 0);
#pragma unroll
      for (int am = 0; am < 4; ++am)
        acc[am] = __builtin_amdgcn_mfma_f32_16x16x32_bf16(ah[am][1], bl1, acc[am], 0, 0, 0);

      // running max/argmax (C layout: col=lane&15, row=(lane>>4)*4+reg)
      const int jc = c * 64 + bn * 16 + l15;
      const bool jok = jc < N_ITEMS;
#pragma unroll
      for (int am = 0; am < 4; ++am)
#pragma unroll
        for (int r = 0; r < 4; ++r) {
          const int sl = am * 4 + r;
          float v = (jok && jc != self_[sl]) ? acc[am][r] : -3.4e38f;
          if (v > bs[sl]) { bs[sl] = v; bj[sl] = (unsigned)jc; }
        }
    }
  }

  // ---- reduce across the 16 lanes sharing kq (xor masks stay in-group) ----
#pragma unroll
  for (int off = 1; off < 16; off <<= 1) {
#pragma unroll
    for (int sl = 0; sl < 16; ++sl) {
      float    os = __shfl_xor(bs[sl], off, 64);
      unsigned oj = (unsigned)__shfl_xor((int)bj[sl], off, 64);
      if (os > bs[sl] || (os == bs[sl] && oj < bj[sl])) { bs[sl] = os; bj[sl] = oj; }
    }
  }
  if (l15 == 0) {
#pragma unroll
    for (int am = 0; am < 4; ++am)
#pragma unroll
      for (int r = 0; r < 4; ++r) {
        const int sl = am * 4 + r;
        union { float f; int i; unsigned u; } cv; cv.f = bs[sl];
        unsigned mu = (cv.i < 0) ? ~cv.u : (cv.u | 0x80000000u);
        unsigned long long key = ((unsigned long long)mu << 32) |
                                 (unsigned long long)(0xFFFFFFFFu - bj[sl]);
        atomicMax(best + m0 + am * 16 + kq * 4 + r, key);
      }
  }
}

__global__ void extract_kernel(const unsigned long long* __restrict__ best,
                               const float* __restrict__ mn,
                               const float* __restrict__ mx,
                               float* __restrict__ out) {
  int t = blockIdx.x * blockDim.x + threadIdx.x;
  if (t >= BATCH) return;
  unsigned long long k = best[t];
  unsigned mu = (unsigned)(k >> 32);
  unsigned j  = 0xFFFFFFFFu - (unsigned)(k & 0xFFFFFFFFull);
  union { unsigned u; float f; } cv;
  cv.u = (mu & 0x80000000u) ? (mu & 0x7FFFFFFFu) : ~mu;
  float s = cv.f;
  float lo = mn[0], hi = mx[0];
  out[t] = (float)(j + 1);                 // indices = argmax + 1
  out[BATCH + t] = (s - lo) / (hi - lo);   // normalized score
}

extern "C" void kernel_launch(void* const* d_in, const int* in_sizes, int n_in,
                              void* d_out, int out_size, void* d_ws, size_t ws_size,
                              hipStream_t stream) {
  const float* emb = (const float*)d_in[0];
  const int* idx   = (const int*)d_in[1];
  const float* mn  = (const float*)d_in[2];
  const float* mx  = (const float*)d_in[3];
  unsigned long long* best = (unsigned long long*)d_ws;

  hipMemsetAsync(d_ws, 0, BATCH * sizeof(unsigned long long), stream);

  sim_kernel<<<dim3(4 * JG), dim3(256), 0, stream>>>(emb, idx, best);
  extract_kernel<<<dim3((BATCH + 255) / 256), dim3(256), 0, stream>>>(
      best, mn, mx, (float*)d_out);
}